// Round 5
// baseline (527.390 us; speedup 1.0000x reference)
//
#include <hip/hip_runtime.h>
#include <math.h>

#define N 2048
#define D 256
#define H 8
#define DK 32
#define L 4
#define DFF 1024
#define NEDGE 5
#define JC 4  // attention j-chunks (flash-decode split)

typedef short short8 __attribute__((ext_vector_type(8)));
typedef float floatx4 __attribute__((ext_vector_type(4)));

__device__ __forceinline__ unsigned short f2bf(float f) {
  unsigned int u = __float_as_uint(f);
  u += 0x7fffu + ((u >> 16) & 1u);
  return (unsigned short)(u >> 16);
}

__device__ __forceinline__ void async16(unsigned short* lds, const unsigned short* g) {
  __builtin_amdgcn_global_load_lds(
      (const __attribute__((address_space(1))) unsigned int*)g,
      (__attribute__((address_space(3))) unsigned int*)lds, 16, 0, 0);
}

// ---- eidx int32 -> uint8 --------------------------------------------------
__global__ __launch_bounds__(256) void k_e8(const int* __restrict__ e,
                                            unsigned int* __restrict__ e8) {
  int i = blockIdx.x * 256 + threadIdx.x;  // over N*N/4
  int4 v = ((const int4*)e)[i];
  e8[i] = (unsigned int)(v.x & 0xff) | ((unsigned int)(v.y & 0xff) << 8) |
          ((unsigned int)(v.z & 0xff) << 16) | ((unsigned int)(v.w & 0xff) << 24);
}

// ---- weight transpose+convert: src fp32 (K_,N_) -> dst bf16 (N_,K_) -------
__global__ __launch_bounds__(256) void k_wt(const float* __restrict__ src, size_t srcL,
                                            int K_, int N_,
                                            unsigned short* __restrict__ dst, size_t dstL,
                                            int rowOff) {
  __shared__ float t[32][33];
  int l = blockIdx.z;
  const float* s = src + (size_t)l * srcL;
  unsigned short* d = dst + (size_t)l * dstL;
  int n0 = blockIdx.x * 32, k0 = blockIdx.y * 32;
  int tx = threadIdx.x, ty = threadIdx.y;
#pragma unroll
  for (int i = 0; i < 32; i += 8) t[ty + i][tx] = s[(size_t)(k0 + ty + i) * N_ + n0 + tx];
  __syncthreads();
#pragma unroll
  for (int i = 0; i < 32; i += 8)
    d[(size_t)(rowOff + n0 + ty + i) * K_ + k0 + tx] = f2bf(t[tx][ty + i]);
}

// ---------------- embed ----------------------------------------------------
__global__ __launch_bounds__(256) void k_embed(const int* __restrict__ nt,
                                               const float* __restrict__ emb,
                                               float* __restrict__ x,
                                               unsigned short* __restrict__ xb) {
  int n = blockIdx.x, d = threadIdx.x;
  float v = emb[nt[n] * D + d];
  x[n * D + d] = v;
  xb[n * D + d] = f2bf(v);
}

// ---- bf16 MFMA GEMM (64x64 tile, 2-panel BK=64): C=A@Bt^T [+bias][+gelu] --
__global__ __launch_bounds__(256) void k_mm(const unsigned short* __restrict__ A,
                                            const unsigned short* __restrict__ Bt,
                                            int Nn, int K,
                                            const float* __restrict__ bias,
                                            int gelu,
                                            float* __restrict__ outf,
                                            unsigned short* __restrict__ outb) {
  __shared__ unsigned short As[2][64 * 32];
  __shared__ unsigned short Bs[2][64 * 32];
  int tid = threadIdx.x;
  int w = tid >> 6, lane = tid & 63, quad = lane >> 4, c16 = lane & 15;
  int bm = blockIdx.y * 64, bn = blockIdx.x * 64;
  int srow = w * 16 + (lane >> 2);
  int schk = (lane & 3) * 8;
  const unsigned short* gA = A + (size_t)(bm + srow) * K + schk;
  const unsigned short* gB = Bt + (size_t)(bn + srow) * K + schk;

  floatx4 acc[4] = {{0.f, 0.f, 0.f, 0.f}, {0.f, 0.f, 0.f, 0.f},
                    {0.f, 0.f, 0.f, 0.f}, {0.f, 0.f, 0.f, 0.f}};
  for (int k0 = 0; k0 < K; k0 += 64) {
#pragma unroll
    for (int p = 0; p < 2; ++p) {
      async16(&As[p][w * 512 + lane * 8], gA + k0 + p * 32);
      async16(&Bs[p][w * 512 + lane * 8], gB + k0 + p * 32);
    }
    __syncthreads();
#pragma unroll
    for (int p = 0; p < 2; ++p) {
      short8 a = *(const short8*)&As[p][(w * 16 + c16) * 32 + quad * 8];
#pragma unroll
      for (int nt = 0; nt < 4; ++nt) {
        short8 b = *(const short8*)&Bs[p][(nt * 16 + c16) * 32 + quad * 8];
        acc[nt] = __builtin_amdgcn_mfma_f32_16x16x32_bf16(a, b, acc[nt], 0, 0, 0);
      }
    }
    __syncthreads();
  }
#pragma unroll
  for (int nt = 0; nt < 4; ++nt) {
#pragma unroll
    for (int e = 0; e < 4; ++e) {
      int row = bm + w * 16 + quad * 4 + e;
      int col = bn + nt * 16 + c16;
      float v = acc[nt][e] + bias[col];
      if (gelu) v = 0.5f * v * (1.0f + erff(v * 0.70710678118654752f));
      if (outf) outf[(size_t)row * Nn + col] = v;
      if (outb) outb[(size_t)row * Nn + col] = f2bf(v);
    }
  }
}

// ---- fused QKV GEMM (2-panel BK=64): writes qb,kb (N,D) and vt (D,N) ------
__global__ __launch_bounds__(256) void k_mm_qkv(const unsigned short* __restrict__ A,
                                                const unsigned short* __restrict__ Bt,
                                                unsigned short* __restrict__ qb,
                                                unsigned short* __restrict__ kb,
                                                unsigned short* __restrict__ vtb) {
  const int K = D;
  __shared__ unsigned short As[2][64 * 32];
  __shared__ unsigned short Bs[2][64 * 32];
  int tid = threadIdx.x;
  int w = tid >> 6, lane = tid & 63, quad = lane >> 4, c16 = lane & 15;
  int bm = blockIdx.y * 64, bn = blockIdx.x * 64;
  int srow = w * 16 + (lane >> 2);
  int schk = (lane & 3) * 8;
  const unsigned short* gA = A + (size_t)(bm + srow) * K + schk;
  const unsigned short* gB = Bt + (size_t)(bn + srow) * K + schk;

  floatx4 acc[4] = {{0.f, 0.f, 0.f, 0.f}, {0.f, 0.f, 0.f, 0.f},
                    {0.f, 0.f, 0.f, 0.f}, {0.f, 0.f, 0.f, 0.f}};
  for (int k0 = 0; k0 < K; k0 += 64) {
#pragma unroll
    for (int p = 0; p < 2; ++p) {
      async16(&As[p][w * 512 + lane * 8], gA + k0 + p * 32);
      async16(&Bs[p][w * 512 + lane * 8], gB + k0 + p * 32);
    }
    __syncthreads();
#pragma unroll
    for (int p = 0; p < 2; ++p) {
      short8 a = *(const short8*)&As[p][(w * 16 + c16) * 32 + quad * 8];
#pragma unroll
      for (int nt = 0; nt < 4; ++nt) {
        short8 b = *(const short8*)&Bs[p][(nt * 16 + c16) * 32 + quad * 8];
        acc[nt] = __builtin_amdgcn_mfma_f32_16x16x32_bf16(a, b, acc[nt], 0, 0, 0);
      }
    }
    __syncthreads();
  }
#pragma unroll
  for (int nt = 0; nt < 4; ++nt) {
#pragma unroll
    for (int e = 0; e < 4; ++e) {
      int row = bm + w * 16 + quad * 4 + e;
      int col = bn + nt * 16 + c16;  // q:0-255, k:256-511, v:512-767
      unsigned short bv = f2bf(acc[nt][e]);
      if (col < 512) {
        unsigned short* dst = (col < 256) ? qb : kb;
        dst[(size_t)row * D + (col & 255)] = bv;
      } else {
        vtb[(size_t)(col - 512) * N + row] = bv;
      }
    }
  }
}

// ---- fused GEMM + bias + residual + LayerNorm (full-row tile) -------------
// grid = N/64 blocks; block = 4 waves; wave w: rows [bm+w*16, +16) x all 256 cols.
// LN reduction in-register via shfl_xor across the 16 c16-lanes per quad.
__global__ __launch_bounds__(256) void k_mm_ln(const unsigned short* __restrict__ A,
                                               const unsigned short* __restrict__ Bt,
                                               int K,
                                               const float* __restrict__ bias,
                                               const float* __restrict__ g,
                                               const float* __restrict__ b,
                                               float* __restrict__ x,
                                               unsigned short* __restrict__ xb) {
  __shared__ unsigned short As[2][64 * 32];
  __shared__ unsigned short Bs[2][256 * 32];
  int tid = threadIdx.x;
  int w = tid >> 6, lane = tid & 63, quad = lane >> 4, c16 = lane & 15;
  int bm = blockIdx.x * 64;
  int arow = w * 16 + (lane >> 2);
  int schk = (lane & 3) * 8;
  const unsigned short* gA = A + (size_t)(bm + arow) * K + schk;

  floatx4 acc[16];
#pragma unroll
  for (int nt = 0; nt < 16; ++nt) acc[nt] = (floatx4){0.f, 0.f, 0.f, 0.f};

  for (int k0 = 0; k0 < K; k0 += 64) {
#pragma unroll
    for (int p = 0; p < 2; ++p) {
      async16(&As[p][w * 512 + lane * 8], gA + k0 + p * 32);
#pragma unroll
      for (int c = 0; c < 4; ++c) {
        int brow = w * 64 + c * 16 + (lane >> 2);
        async16(&Bs[p][(w * 64 + c * 16) * 32 + lane * 8],
                Bt + (size_t)brow * K + k0 + p * 32 + schk);
      }
    }
    __syncthreads();
#pragma unroll
    for (int p = 0; p < 2; ++p) {
      short8 a = *(const short8*)&As[p][(w * 16 + c16) * 32 + quad * 8];
#pragma unroll
      for (int nt = 0; nt < 16; ++nt) {
        short8 bfr = *(const short8*)&Bs[p][(nt * 16 + c16) * 32 + quad * 8];
        acc[nt] = __builtin_amdgcn_mfma_f32_16x16x32_bf16(a, bfr, acc[nt], 0, 0, 0);
      }
    }
    __syncthreads();
  }

  // epilogue: +bias, +residual, LayerNorm over the 256 cols of each row
  float tv[16][4];
#pragma unroll
  for (int e = 0; e < 4; ++e) {
    int row = bm + w * 16 + quad * 4 + e;
    float s = 0.f;
#pragma unroll
    for (int nt = 0; nt < 16; ++nt) {
      int col = nt * 16 + c16;
      float v = acc[nt][e] + bias[col] + x[(size_t)row * D + col];
      tv[nt][e] = v;
      s += v;
    }
    s += __shfl_xor(s, 1); s += __shfl_xor(s, 2);
    s += __shfl_xor(s, 4); s += __shfl_xor(s, 8);
    float mn = s * (1.0f / D);
    float vs = 0.f;
#pragma unroll
    for (int nt = 0; nt < 16; ++nt) {
      float c_ = tv[nt][e] - mn;
      vs += c_ * c_;
    }
    vs += __shfl_xor(vs, 1); vs += __shfl_xor(vs, 2);
    vs += __shfl_xor(vs, 4); vs += __shfl_xor(vs, 8);
    float r = rsqrtf(vs * (1.0f / D) + 1e-5f);
#pragma unroll
    for (int nt = 0; nt < 16; ++nt) {
      int col = nt * 16 + c16;
      float o = (tv[nt][e] - mn) * r * g[col] + b[col];
      x[(size_t)row * D + col] = o;
      xb[(size_t)row * D + col] = f2bf(o);
    }
  }
}

// ---- MFMA flash attention, j-split partials -------------------------------
#define PB_STR 72
__global__ __launch_bounds__(512) void k_attn(const unsigned short* __restrict__ qb,
                                              const unsigned short* __restrict__ kb,
                                              const unsigned short* __restrict__ vt,
                                              const unsigned char* __restrict__ e8,
                                              const float* __restrict__ eb,
                                              float* __restrict__ Opart,
                                              float* __restrict__ mpart,
                                              float* __restrict__ lpart) {
  __shared__ unsigned short Pb[H][16 * PB_STR];
  __shared__ float ebh[H][NEDGE];
  const int tid = threadIdx.x;
  const int h = tid >> 6;
  const int lane = tid & 63;
  const int quad = lane >> 4;
  const int c16 = lane & 15;
  const int r0 = blockIdx.x * 16;
  const int jc = blockIdx.y;

  if (tid < NEDGE * H) ebh[tid % H][tid / H] = eb[tid];
  __syncthreads();

  short8 aq = *(const short8*)&qb[(size_t)(r0 + c16) * D + h * DK + quad * 8];

  float mrow[4] = {-INFINITY, -INFINITY, -INFINITY, -INFINITY};
  float lrow[4] = {0.f, 0.f, 0.f, 0.f};
  floatx4 O0 = {0.f, 0.f, 0.f, 0.f};
  floatx4 O1 = {0.f, 0.f, 0.f, 0.f};
  const float scale = 0.17677669529663688f;

  for (int j0 = jc * (N / JC); j0 < (jc + 1) * (N / JC); j0 += 64) {
    floatx4 Sc[4];
#pragma unroll
    for (int t = 0; t < 4; ++t) {
      short8 bk = *(const short8*)&kb[(size_t)(j0 + t * 16 + c16) * D + h * DK + quad * 8];
      floatx4 z = {0.f, 0.f, 0.f, 0.f};
      Sc[t] = __builtin_amdgcn_mfma_f32_16x16x32_bf16(aq, bk, z, 0, 0, 0);
    }
    float s[4][4];
#pragma unroll
    for (int t = 0; t < 4; ++t) {
#pragma unroll
      for (int e = 0; e < 4; ++e) {
        int ei = e8[(size_t)(r0 + quad * 4 + e) * N + j0 + t * 16 + c16];
        s[t][e] = Sc[t][e] * scale + ebh[h][ei];
      }
    }
#pragma unroll
    for (int e = 0; e < 4; ++e) {
      float tm = fmaxf(fmaxf(s[0][e], s[1][e]), fmaxf(s[2][e], s[3][e]));
      tm = fmaxf(tm, __shfl_xor(tm, 1));
      tm = fmaxf(tm, __shfl_xor(tm, 2));
      tm = fmaxf(tm, __shfl_xor(tm, 4));
      tm = fmaxf(tm, __shfl_xor(tm, 8));
      float mn = fmaxf(mrow[e], tm);
      float alpha = __expf(mrow[e] - mn);
      mrow[e] = mn;
      float ps = 0.f;
#pragma unroll
      for (int t = 0; t < 4; ++t) {
        float p = __expf(s[t][e] - mn);
        s[t][e] = p;
        ps += p;
      }
      ps += __shfl_xor(ps, 1);
      ps += __shfl_xor(ps, 2);
      ps += __shfl_xor(ps, 4);
      ps += __shfl_xor(ps, 8);
      lrow[e] = lrow[e] * alpha + ps;
      O0[e] *= alpha;
      O1[e] *= alpha;
    }
#pragma unroll
    for (int t = 0; t < 4; ++t)
#pragma unroll
      for (int e = 0; e < 4; ++e)
        Pb[h][(quad * 4 + e) * PB_STR + t * 16 + c16] = f2bf(s[t][e]);
    asm volatile("" ::: "memory");
#pragma unroll
    for (int jj = 0; jj < 2; ++jj) {
      short8 ap = *(const short8*)&Pb[h][c16 * PB_STR + jj * 32 + quad * 8];
      short8 bv0 = *(const short8*)&vt[(size_t)(h * DK + c16) * N + j0 + jj * 32 + quad * 8];
      short8 bv1 = *(const short8*)&vt[(size_t)(h * DK + 16 + c16) * N + j0 + jj * 32 + quad * 8];
      O0 = __builtin_amdgcn_mfma_f32_16x16x32_bf16(ap, bv0, O0, 0, 0, 0);
      O1 = __builtin_amdgcn_mfma_f32_16x16x32_bf16(ap, bv1, O1, 0, 0, 0);
    }
    asm volatile("" ::: "memory");
  }

#pragma unroll
  for (int e = 0; e < 4; ++e) {
    int row = r0 + quad * 4 + e;
    size_t ob = ((size_t)jc * N + row) * D + h * DK;
    Opart[ob + c16] = O0[e];
    Opart[ob + 16 + c16] = O1[e];
    if (c16 == 0) {
      mpart[((size_t)jc * N + row) * H + h] = mrow[e];
      lpart[((size_t)jc * N + row) * H + h] = lrow[e];
    }
  }
}

// ---- combine JC partial chunks -> attention output (bf16) -----------------
__global__ __launch_bounds__(256) void k_attn_comb(const float* __restrict__ Opart,
                                                   const float* __restrict__ mpart,
                                                   const float* __restrict__ lpart,
                                                   unsigned short* __restrict__ aob) {
  int row = blockIdx.x, d = threadIdx.x, h = d >> 5;
  float m[JC];
  float mstar = -INFINITY;
#pragma unroll
  for (int c = 0; c < JC; ++c) {
    m[c] = mpart[((size_t)c * N + row) * H + h];
    mstar = fmaxf(mstar, m[c]);
  }
  float lstar = 0.f, o = 0.f;
#pragma unroll
  for (int c = 0; c < JC; ++c) {
    float wgt = __expf(m[c] - mstar);
    lstar += wgt * lpart[((size_t)c * N + row) * H + h];
    o += wgt * Opart[((size_t)c * N + row) * D + d];
  }
  aob[(size_t)row * D + d] = f2bf(o / lstar);
}

// ---- pool phase 1: 64 blocks x 32 rows -> partial sum/max -----------------
__global__ __launch_bounds__(256) void k_pool1(const float* __restrict__ x,
                                               float* __restrict__ part) {
  int b = blockIdx.x, d = threadIdx.x;
  float sum = 0.f, mx = -INFINITY;
  for (int n = b * 32; n < b * 32 + 32; ++n) {
    float v = x[(size_t)n * D + d];
    sum += v;
    mx = fmaxf(mx, v);
  }
  part[(size_t)b * 2 * D + d] = sum;
  part[(size_t)b * 2 * D + D + d] = mx;
}

// ---- pool phase 2: reduce 64 partials + project ---------------------------
__global__ __launch_bounds__(256) void k_pool2(const float* __restrict__ part,
                                               const float* __restrict__ Wr,
                                               const float* __restrict__ br,
                                               float* __restrict__ out) {
  __shared__ float pooled[2 * D];
  int d = threadIdx.x;
  float sum = 0.f, mx = -INFINITY;
  for (int b = 0; b < 64; ++b) {
    sum += part[(size_t)b * 2 * D + d];
    mx = fmaxf(mx, part[(size_t)b * 2 * D + D + d]);
  }
  pooled[d] = sum * (1.0f / N);
  pooled[D + d] = mx;
  __syncthreads();
  float acc = br[d];
  for (int k2 = 0; k2 < 2 * D; ++k2) acc = fmaf(pooled[k2], Wr[(size_t)k2 * D + d], acc);
  out[d] = acc;
}

extern "C" void kernel_launch(void* const* d_in, const int* in_sizes, int n_in,
                              void* d_out, int out_size, void* d_ws, size_t ws_size,
                              hipStream_t stream) {
  const int* node_types = (const int*)d_in[0];
  const int* eidx = (const int*)d_in[1];
  const float* node_emb = (const float*)d_in[2];
  const float* Wq = (const float*)d_in[3];
  const float* Wk = (const float*)d_in[4];
  const float* Wv = (const float*)d_in[5];
  const float* Wo = (const float*)d_in[6];
  const float* bo = (const float*)d_in[7];
  const float* eb = (const float*)d_in[8];
  const float* W1 = (const float*)d_in[9];
  const float* b1 = (const float*)d_in[10];
  const float* W2 = (const float*)d_in[11];
  const float* b2 = (const float*)d_in[12];
  const float* g1 = (const float*)d_in[13];
  const float* be1 = (const float*)d_in[14];
  const float* g2 = (const float*)d_in[15];
  const float* be2 = (const float*)d_in[16];
  const float* Wr = (const float*)d_in[17];
  const float* br = (const float*)d_in[18];
  float* out = (float*)d_out;

  // workspace layout
  float* x = (float*)d_ws;                      // N*D fp32
  float* Opart = x + (size_t)N * D;             // JC*N*D fp32
  float* mpart = Opart + (size_t)JC * N * D;    // JC*N*H
  float* lpart = mpart + (size_t)JC * N * H;    // JC*N*H
  float* ppool = lpart + (size_t)JC * N * H;    // 64*2*D
  unsigned short* xb = (unsigned short*)(ppool + 64 * 2 * D);
  unsigned short* qb = xb + (size_t)N * D;
  unsigned short* kb = qb + (size_t)N * D;
  unsigned short* vtb = kb + (size_t)N * D;     // (D, N) head-major d
  unsigned short* aob = vtb + (size_t)N * D;
  unsigned short* hb = aob + (size_t)N * D;     // N*DFF
  unsigned short* wqkvb = hb + (size_t)N * DFF; // L x (768, 256)
  unsigned short* wob = wqkvb + (size_t)L * 768 * D;
  unsigned short* w1b = wob + (size_t)L * D * D;
  unsigned short* w2b = w1b + (size_t)L * DFF * D;
  unsigned char* e8 = (unsigned char*)(w2b + (size_t)L * D * DFF);  // N*N bytes

  k_e8<<<(N * N / 4) / 256, 256, 0, stream>>>(eidx, (unsigned int*)e8);

  dim3 tb(32, 8);
  k_wt<<<dim3(D / 32, D / 32, L), tb, 0, stream>>>(Wq, (size_t)D * D, D, D, wqkvb, 768 * D, 0);
  k_wt<<<dim3(D / 32, D / 32, L), tb, 0, stream>>>(Wk, (size_t)D * D, D, D, wqkvb, 768 * D, 256);
  k_wt<<<dim3(D / 32, D / 32, L), tb, 0, stream>>>(Wv, (size_t)D * D, D, D, wqkvb, 768 * D, 512);
  k_wt<<<dim3(D / 32, D / 32, L), tb, 0, stream>>>(Wo, (size_t)D * D, D, D, wob, D * D, 0);
  k_wt<<<dim3(DFF / 32, D / 32, L), tb, 0, stream>>>(W1, (size_t)D * DFF, D, DFF, w1b, DFF * D, 0);
  k_wt<<<dim3(D / 32, DFF / 32, L), tb, 0, stream>>>(W2, (size_t)DFF * D, DFF, D, w2b, D * DFF, 0);

  k_embed<<<N, 256, 0, stream>>>(node_types, node_emb, x, xb);

  for (int l = 0; l < L; ++l) {
    k_mm_qkv<<<dim3(768 / 64, N / 64), 256, 0, stream>>>(
        xb, wqkvb + (size_t)l * 768 * D, qb, kb, vtb);

    k_attn<<<dim3(N / 16, JC), 512, 0, stream>>>(qb, kb, vtb, e8,
                                                 eb + (size_t)l * NEDGE * H,
                                                 Opart, mpart, lpart);
    k_attn_comb<<<N, 256, 0, stream>>>(Opart, mpart, lpart, aob);

    // Wo GEMM + bias + residual + LN1
    k_mm_ln<<<N / 64, 256, 0, stream>>>(aob, wob + (size_t)l * D * D, D,
                                        bo + (size_t)l * D,
                                        g1 + (size_t)l * D, be1 + (size_t)l * D, x, xb);

    // FFN1 GEMM + bias + GELU
    k_mm<<<dim3(DFF / 64, N / 64), 256, 0, stream>>>(
        xb, w1b + (size_t)l * DFF * D, DFF, D, b1 + (size_t)l * DFF, 1, (float*)nullptr, hb);

    // FFN2 GEMM + bias + residual + LN2
    k_mm_ln<<<N / 64, 256, 0, stream>>>(hb, w2b + (size_t)l * D * DFF, DFF,
                                        b2 + (size_t)l * D,
                                        g2 + (size_t)l * D, be2 + (size_t)l * D, x, xb);
  }

  k_pool1<<<64, 256, 0, stream>>>(x, ppool);
  k_pool2<<<1, 256, 0, stream>>>(ppool, Wr, br, out);
}

// Round 6
// 494.765 us; speedup vs baseline: 1.0659x; 1.0659x over previous
//
#include <hip/hip_runtime.h>
#include <math.h>

#define N 2048
#define D 256
#define H 8
#define DK 32
#define L 4
#define DFF 1024
#define NEDGE 5
#define JC 4  // attention j-chunks (flash-decode split)

typedef short short8 __attribute__((ext_vector_type(8)));
typedef float floatx4 __attribute__((ext_vector_type(4)));

__device__ __forceinline__ unsigned short f2bf(float f) {
  unsigned int u = __float_as_uint(f);
  u += 0x7fffu + ((u >> 16) & 1u);
  return (unsigned short)(u >> 16);
}

__device__ __forceinline__ void async16(unsigned short* lds, const unsigned short* g) {
  __builtin_amdgcn_global_load_lds(
      (const __attribute__((address_space(1))) unsigned int*)g,
      (__attribute__((address_space(3))) unsigned int*)lds, 16, 0, 0);
}

// ---- eidx int32 -> uint8 --------------------------------------------------
__global__ __launch_bounds__(256) void k_e8(const int* __restrict__ e,
                                            unsigned int* __restrict__ e8) {
  int i = blockIdx.x * 256 + threadIdx.x;  // over N*N/4
  int4 v = ((const int4*)e)[i];
  e8[i] = (unsigned int)(v.x & 0xff) | ((unsigned int)(v.y & 0xff) << 8) |
          ((unsigned int)(v.z & 0xff) << 16) | ((unsigned int)(v.w & 0xff) << 24);
}

// ---- 4x D x D weight transpose+convert in one launch ----------------------
__global__ __launch_bounds__(256) void k_wt4(const float* __restrict__ Wq,
                                             const float* __restrict__ Wk,
                                             const float* __restrict__ Wv,
                                             const float* __restrict__ Wo,
                                             unsigned short* __restrict__ wqkvb,
                                             unsigned short* __restrict__ wob) {
  __shared__ float t[32][33];
  int z = blockIdx.z, l = z >> 2, which = z & 3;
  const float* s = (which == 0 ? Wq : which == 1 ? Wk : which == 2 ? Wv : Wo) + (size_t)l * D * D;
  unsigned short* d;
  int rowOff;
  if (which < 3) { d = wqkvb + (size_t)l * 768 * D; rowOff = which * 256; }
  else { d = wob + (size_t)l * D * D; rowOff = 0; }
  int n0 = blockIdx.x * 32, k0 = blockIdx.y * 32;
  int tx = threadIdx.x, ty = threadIdx.y;
#pragma unroll
  for (int i = 0; i < 32; i += 8) t[ty + i][tx] = s[(size_t)(k0 + ty + i) * D + n0 + tx];
  __syncthreads();
#pragma unroll
  for (int i = 0; i < 32; i += 8)
    d[(size_t)(rowOff + n0 + ty + i) * D + k0 + tx] = f2bf(t[tx][ty + i]);
}

// ---- generic weight transpose+convert: src fp32 (K_,N_) -> dst bf16 (N_,K_)
__global__ __launch_bounds__(256) void k_wt(const float* __restrict__ src, size_t srcL,
                                            int K_, int N_,
                                            unsigned short* __restrict__ dst, size_t dstL) {
  __shared__ float t[32][33];
  int l = blockIdx.z;
  const float* s = src + (size_t)l * srcL;
  unsigned short* d = dst + (size_t)l * dstL;
  int n0 = blockIdx.x * 32, k0 = blockIdx.y * 32;
  int tx = threadIdx.x, ty = threadIdx.y;
#pragma unroll
  for (int i = 0; i < 32; i += 8) t[ty + i][tx] = s[(size_t)(k0 + ty + i) * N_ + n0 + tx];
  __syncthreads();
#pragma unroll
  for (int i = 0; i < 32; i += 8)
    d[(size_t)(n0 + ty + i) * K_ + k0 + tx] = f2bf(t[tx][ty + i]);
}

// ---------------- embed ----------------------------------------------------
__global__ __launch_bounds__(256) void k_embed(const int* __restrict__ nt,
                                               const float* __restrict__ emb,
                                               float* __restrict__ x,
                                               unsigned short* __restrict__ xb) {
  int n = blockIdx.x, d = threadIdx.x;
  float v = emb[nt[n] * D + d];
  x[n * D + d] = v;
  xb[n * D + d] = f2bf(v);
}

// ---- fused QKV GEMM (2-panel BK=64): writes qb,kb (N,D) and vt (D,N) ------
__global__ __launch_bounds__(256) void k_mm_qkv(const unsigned short* __restrict__ A,
                                                const unsigned short* __restrict__ Bt,
                                                unsigned short* __restrict__ qb,
                                                unsigned short* __restrict__ kb,
                                                unsigned short* __restrict__ vtb) {
  const int K = D;
  __shared__ unsigned short As[2][64 * 32];
  __shared__ unsigned short Bs[2][64 * 32];
  int tid = threadIdx.x;
  int w = tid >> 6, lane = tid & 63, quad = lane >> 4, c16 = lane & 15;
  int bm = blockIdx.y * 64, bn = blockIdx.x * 64;
  int srow = w * 16 + (lane >> 2);
  int schk = (lane & 3) * 8;
  const unsigned short* gA = A + (size_t)(bm + srow) * K + schk;
  const unsigned short* gB = Bt + (size_t)(bn + srow) * K + schk;

  floatx4 acc[4] = {{0.f, 0.f, 0.f, 0.f}, {0.f, 0.f, 0.f, 0.f},
                    {0.f, 0.f, 0.f, 0.f}, {0.f, 0.f, 0.f, 0.f}};
  for (int k0 = 0; k0 < K; k0 += 64) {
#pragma unroll
    for (int p = 0; p < 2; ++p) {
      async16(&As[p][w * 512 + lane * 8], gA + k0 + p * 32);
      async16(&Bs[p][w * 512 + lane * 8], gB + k0 + p * 32);
    }
    __syncthreads();
#pragma unroll
    for (int p = 0; p < 2; ++p) {
      short8 a = *(const short8*)&As[p][(w * 16 + c16) * 32 + quad * 8];
#pragma unroll
      for (int nt = 0; nt < 4; ++nt) {
        short8 b = *(const short8*)&Bs[p][(nt * 16 + c16) * 32 + quad * 8];
        acc[nt] = __builtin_amdgcn_mfma_f32_16x16x32_bf16(a, b, acc[nt], 0, 0, 0);
      }
    }
    __syncthreads();
  }
#pragma unroll
  for (int nt = 0; nt < 4; ++nt) {
#pragma unroll
    for (int e = 0; e < 4; ++e) {
      int row = bm + w * 16 + quad * 4 + e;
      int col = bn + nt * 16 + c16;  // q:0-255, k:256-511, v:512-767
      unsigned short bv = f2bf(acc[nt][e]);
      if (col < 512) {
        unsigned short* dst = (col < 256) ? qb : kb;
        dst[(size_t)row * D + (col & 255)] = bv;
      } else {
        vtb[(size_t)(col - 512) * N + row] = bv;
      }
    }
  }
}

// ---- MFMA flash attention, j-split partials -------------------------------
#define PB_STR 72
__global__ __launch_bounds__(512) void k_attn(const unsigned short* __restrict__ qb,
                                              const unsigned short* __restrict__ kb,
                                              const unsigned short* __restrict__ vt,
                                              const unsigned char* __restrict__ e8,
                                              const float* __restrict__ eb,
                                              float* __restrict__ Opart,
                                              float* __restrict__ mpart,
                                              float* __restrict__ lpart) {
  __shared__ unsigned short Pb[H][16 * PB_STR];
  __shared__ float ebh[H][NEDGE];
  const int tid = threadIdx.x;
  const int h = tid >> 6;
  const int lane = tid & 63;
  const int quad = lane >> 4;
  const int c16 = lane & 15;
  const int r0 = blockIdx.x * 16;
  const int jc = blockIdx.y;

  if (tid < NEDGE * H) ebh[tid % H][tid / H] = eb[tid];
  __syncthreads();

  short8 aq = *(const short8*)&qb[(size_t)(r0 + c16) * D + h * DK + quad * 8];

  float mrow[4] = {-INFINITY, -INFINITY, -INFINITY, -INFINITY};
  float lrow[4] = {0.f, 0.f, 0.f, 0.f};
  floatx4 O0 = {0.f, 0.f, 0.f, 0.f};
  floatx4 O1 = {0.f, 0.f, 0.f, 0.f};
  const float scale = 0.17677669529663688f;

  for (int j0 = jc * (N / JC); j0 < (jc + 1) * (N / JC); j0 += 64) {
    floatx4 Sc[4];
#pragma unroll
    for (int t = 0; t < 4; ++t) {
      short8 bk = *(const short8*)&kb[(size_t)(j0 + t * 16 + c16) * D + h * DK + quad * 8];
      floatx4 z = {0.f, 0.f, 0.f, 0.f};
      Sc[t] = __builtin_amdgcn_mfma_f32_16x16x32_bf16(aq, bk, z, 0, 0, 0);
    }
    float s[4][4];
#pragma unroll
    for (int t = 0; t < 4; ++t) {
#pragma unroll
      for (int e = 0; e < 4; ++e) {
        int ei = e8[(size_t)(r0 + quad * 4 + e) * N + j0 + t * 16 + c16];
        s[t][e] = Sc[t][e] * scale + ebh[h][ei];
      }
    }
#pragma unroll
    for (int e = 0; e < 4; ++e) {
      float tm = fmaxf(fmaxf(s[0][e], s[1][e]), fmaxf(s[2][e], s[3][e]));
      tm = fmaxf(tm, __shfl_xor(tm, 1));
      tm = fmaxf(tm, __shfl_xor(tm, 2));
      tm = fmaxf(tm, __shfl_xor(tm, 4));
      tm = fmaxf(tm, __shfl_xor(tm, 8));
      float mn = fmaxf(mrow[e], tm);
      float alpha = __expf(mrow[e] - mn);
      mrow[e] = mn;
      float ps = 0.f;
#pragma unroll
      for (int t = 0; t < 4; ++t) {
        float p = __expf(s[t][e] - mn);
        s[t][e] = p;
        ps += p;
      }
      ps += __shfl_xor(ps, 1);
      ps += __shfl_xor(ps, 2);
      ps += __shfl_xor(ps, 4);
      ps += __shfl_xor(ps, 8);
      lrow[e] = lrow[e] * alpha + ps;
      O0[e] *= alpha;
      O1[e] *= alpha;
    }
#pragma unroll
    for (int t = 0; t < 4; ++t)
#pragma unroll
      for (int e = 0; e < 4; ++e)
        Pb[h][(quad * 4 + e) * PB_STR + t * 16 + c16] = f2bf(s[t][e]);
    asm volatile("" ::: "memory");
#pragma unroll
    for (int jj = 0; jj < 2; ++jj) {
      short8 ap = *(const short8*)&Pb[h][c16 * PB_STR + jj * 32 + quad * 8];
      short8 bv0 = *(const short8*)&vt[(size_t)(h * DK + c16) * N + j0 + jj * 32 + quad * 8];
      short8 bv1 = *(const short8*)&vt[(size_t)(h * DK + 16 + c16) * N + j0 + jj * 32 + quad * 8];
      O0 = __builtin_amdgcn_mfma_f32_16x16x32_bf16(ap, bv0, O0, 0, 0, 0);
      O1 = __builtin_amdgcn_mfma_f32_16x16x32_bf16(ap, bv1, O1, 0, 0, 0);
    }
    asm volatile("" ::: "memory");
  }

#pragma unroll
  for (int e = 0; e < 4; ++e) {
    int row = r0 + quad * 4 + e;
    size_t ob = ((size_t)jc * N + row) * D + h * DK;
    Opart[ob + c16] = O0[e];
    Opart[ob + 16 + c16] = O1[e];
    if (c16 == 0) {
      mpart[((size_t)jc * N + row) * H + h] = mrow[e];
      lpart[((size_t)jc * N + row) * H + h] = lrow[e];
    }
  }
}

// ---- fused: combine partials -> Wo GEMM -> bias+residual+LN1 --------------
// grid N/16 = 128 blocks, 512 threads (8 waves). Wave w: 16 rows x cols [w*32, w*32+32).
// B-frags read directly from global (L2-hot wob). No barriers in K-loop.
#define AO_STR 264
__global__ __launch_bounds__(512) void k_wo(const float* __restrict__ Opart,
                                            const float* __restrict__ mpart,
                                            const float* __restrict__ lpart,
                                            const unsigned short* __restrict__ wob,
                                            const float* __restrict__ bias,
                                            const float* __restrict__ g,
                                            const float* __restrict__ b,
                                            float* __restrict__ x,
                                            unsigned short* __restrict__ xb) {
  __shared__ unsigned short ao_s[16 * AO_STR];
  __shared__ float redS[8][16];
  __shared__ float redQ[8][16];
  const int tid = threadIdx.x;
  const int w = tid >> 6, lane = tid & 63, quad = lane >> 4, c16 = lane & 15;
  const int r0 = blockIdx.x * 16;

  // ---- combine phase: 16 rows x 256 cols; thread: row=tid>>5, 8 cols ----
  {
    int trow = tid >> 5;
    int tcol = (tid & 31) * 8;
    int hh = tcol >> 5;
    int row = r0 + trow;
    float m[JC], mstar = -INFINITY;
#pragma unroll
    for (int c = 0; c < JC; ++c) {
      m[c] = mpart[((size_t)c * N + row) * H + hh];
      mstar = fmaxf(mstar, m[c]);
    }
    float lstar = 0.f;
    float o[8] = {};
#pragma unroll
    for (int c = 0; c < JC; ++c) {
      float wgt = __expf(m[c] - mstar);
      lstar += wgt * lpart[((size_t)c * N + row) * H + hh];
      const float* op = Opart + ((size_t)c * N + row) * D + tcol;
      float4 v0 = *(const float4*)op;
      float4 v1 = *(const float4*)(op + 4);
      o[0] += wgt * v0.x; o[1] += wgt * v0.y; o[2] += wgt * v0.z; o[3] += wgt * v0.w;
      o[4] += wgt * v1.x; o[5] += wgt * v1.y; o[6] += wgt * v1.z; o[7] += wgt * v1.w;
    }
    float inv = 1.0f / lstar;
#pragma unroll
    for (int j = 0; j < 8; ++j) ao_s[trow * AO_STR + tcol + j] = f2bf(o[j] * inv);
  }
  __syncthreads();

  // ---- Wo GEMM: wave w cols [w*32, +32), K=256, B direct from global ----
  floatx4 acc[2] = {{0.f, 0.f, 0.f, 0.f}, {0.f, 0.f, 0.f, 0.f}};
#pragma unroll
  for (int kc = 0; kc < 8; ++kc) {
    short8 a = *(const short8*)&ao_s[c16 * AO_STR + kc * 32 + quad * 8];
#pragma unroll
    for (int nt = 0; nt < 2; ++nt) {
      int col = w * 32 + nt * 16 + c16;
      short8 bf = *(const short8*)&wob[(size_t)col * D + kc * 32 + quad * 8];
      acc[nt] = __builtin_amdgcn_mfma_f32_16x16x32_bf16(a, bf, acc[nt], 0, 0, 0);
    }
  }

  // ---- epilogue: bias + residual + LN over 256 cols (cross-wave) ----
  float tv[2][4];
  float ps[4];
#pragma unroll
  for (int e = 0; e < 4; ++e) {
    int row = r0 + quad * 4 + e;
    float s = 0.f;
#pragma unroll
    for (int nt = 0; nt < 2; ++nt) {
      int col = w * 32 + nt * 16 + c16;
      float v = acc[nt][e] + bias[col] + x[(size_t)row * D + col];
      tv[nt][e] = v;
      s += v;
    }
    s += __shfl_xor(s, 1); s += __shfl_xor(s, 2);
    s += __shfl_xor(s, 4); s += __shfl_xor(s, 8);
    ps[e] = s;
  }
  if (c16 == 0) {
#pragma unroll
    for (int e = 0; e < 4; ++e) redS[w][quad * 4 + e] = ps[e];
  }
  __syncthreads();
  float mean[4];
#pragma unroll
  for (int e = 0; e < 4; ++e) {
    int r = quad * 4 + e;
    mean[e] = (redS[0][r] + redS[1][r] + redS[2][r] + redS[3][r] +
               redS[4][r] + redS[5][r] + redS[6][r] + redS[7][r]) * (1.0f / D);
    float q = 0.f;
#pragma unroll
    for (int nt = 0; nt < 2; ++nt) {
      float c_ = tv[nt][e] - mean[e];
      q += c_ * c_;
    }
    q += __shfl_xor(q, 1); q += __shfl_xor(q, 2);
    q += __shfl_xor(q, 4); q += __shfl_xor(q, 8);
    ps[e] = q;
  }
  if (c16 == 0) {
#pragma unroll
    for (int e = 0; e < 4; ++e) redQ[w][quad * 4 + e] = ps[e];
  }
  __syncthreads();
#pragma unroll
  for (int e = 0; e < 4; ++e) {
    int r = quad * 4 + e;
    int row = r0 + r;
    float var = (redQ[0][r] + redQ[1][r] + redQ[2][r] + redQ[3][r] +
                 redQ[4][r] + redQ[5][r] + redQ[6][r] + redQ[7][r]) * (1.0f / D);
    float rs = rsqrtf(var + 1e-5f);
#pragma unroll
    for (int nt = 0; nt < 2; ++nt) {
      int col = w * 32 + nt * 16 + c16;
      float o = (tv[nt][e] - mean[e]) * rs * g[col] + b[col];
      x[(size_t)row * D + col] = o;
      xb[(size_t)row * D + col] = f2bf(o);
    }
  }
}

// ---- fused FFN: GEMM1+bias+GELU -> LDS -> GEMM2+bias+residual+LN2 ---------
// grid N/16 = 128 blocks, 512 threads (8 waves).
// Phase1: wave w cols [w*128,+128) of DFF, A direct from global xb, B from w1b.
// Phase2: wave w cols [w*32,+32) of D, A from LDS h, B from w2b.
#define HS_STR 1032
__global__ __launch_bounds__(512) void k_ffn(const unsigned short* __restrict__ xbin,
                                             const unsigned short* __restrict__ w1b,
                                             const unsigned short* __restrict__ w2b,
                                             const float* __restrict__ b1,
                                             const float* __restrict__ b2,
                                             const float* __restrict__ g,
                                             const float* __restrict__ b,
                                             float* __restrict__ x,
                                             unsigned short* __restrict__ xb) {
  __shared__ unsigned short hs[16 * HS_STR];
  __shared__ float redS[8][16];
  __shared__ float redQ[8][16];
  const int tid = threadIdx.x;
  const int w = tid >> 6, lane = tid & 63, quad = lane >> 4, c16 = lane & 15;
  const int r0 = blockIdx.x * 16;

  // ---- phase 1: FFN1, 16 rows x 128 cols per wave ----
  floatx4 acc1[8];
#pragma unroll
  for (int nt = 0; nt < 8; ++nt) acc1[nt] = (floatx4){0.f, 0.f, 0.f, 0.f};
#pragma unroll
  for (int kc = 0; kc < 8; ++kc) {
    short8 a = *(const short8*)&xbin[(size_t)(r0 + c16) * D + kc * 32 + quad * 8];
#pragma unroll
    for (int nt = 0; nt < 8; ++nt) {
      int col = w * 128 + nt * 16 + c16;
      short8 bf = *(const short8*)&w1b[(size_t)col * D + kc * 32 + quad * 8];
      acc1[nt] = __builtin_amdgcn_mfma_f32_16x16x32_bf16(a, bf, acc1[nt], 0, 0, 0);
    }
  }
#pragma unroll
  for (int nt = 0; nt < 8; ++nt) {
#pragma unroll
    for (int e = 0; e < 4; ++e) {
      int col = w * 128 + nt * 16 + c16;
      float v = acc1[nt][e] + b1[col];
      v = 0.5f * v * (1.0f + erff(v * 0.70710678118654752f));
      hs[(quad * 4 + e) * HS_STR + col] = f2bf(v);
    }
  }
  __syncthreads();

  // ---- phase 2: FFN2, 16 rows x 32 cols per wave, K=1024 ----
  floatx4 acc2[2] = {{0.f, 0.f, 0.f, 0.f}, {0.f, 0.f, 0.f, 0.f}};
#pragma unroll 4
  for (int kc = 0; kc < 32; ++kc) {
    short8 a = *(const short8*)&hs[c16 * HS_STR + kc * 32 + quad * 8];
#pragma unroll
    for (int nt = 0; nt < 2; ++nt) {
      int col = w * 32 + nt * 16 + c16;
      short8 bf = *(const short8*)&w2b[(size_t)col * DFF + kc * 32 + quad * 8];
      acc2[nt] = __builtin_amdgcn_mfma_f32_16x16x32_bf16(a, bf, acc2[nt], 0, 0, 0);
    }
  }

  // ---- epilogue: bias + residual + LN2 ----
  float tv[2][4];
  float ps[4];
#pragma unroll
  for (int e = 0; e < 4; ++e) {
    int row = r0 + quad * 4 + e;
    float s = 0.f;
#pragma unroll
    for (int nt = 0; nt < 2; ++nt) {
      int col = w * 32 + nt * 16 + c16;
      float v = acc2[nt][e] + b2[col] + x[(size_t)row * D + col];
      tv[nt][e] = v;
      s += v;
    }
    s += __shfl_xor(s, 1); s += __shfl_xor(s, 2);
    s += __shfl_xor(s, 4); s += __shfl_xor(s, 8);
    ps[e] = s;
  }
  if (c16 == 0) {
#pragma unroll
    for (int e = 0; e < 4; ++e) redS[w][quad * 4 + e] = ps[e];
  }
  __syncthreads();
  float mean[4];
#pragma unroll
  for (int e = 0; e < 4; ++e) {
    int r = quad * 4 + e;
    mean[e] = (redS[0][r] + redS[1][r] + redS[2][r] + redS[3][r] +
               redS[4][r] + redS[5][r] + redS[6][r] + redS[7][r]) * (1.0f / D);
    float q = 0.f;
#pragma unroll
    for (int nt = 0; nt < 2; ++nt) {
      float c_ = tv[nt][e] - mean[e];
      q += c_ * c_;
    }
    q += __shfl_xor(q, 1); q += __shfl_xor(q, 2);
    q += __shfl_xor(q, 4); q += __shfl_xor(q, 8);
    ps[e] = q;
  }
  if (c16 == 0) {
#pragma unroll
    for (int e = 0; e < 4; ++e) redQ[w][quad * 4 + e] = ps[e];
  }
  __syncthreads();
#pragma unroll
  for (int e = 0; e < 4; ++e) {
    int r = quad * 4 + e;
    int row = r0 + r;
    float var = (redQ[0][r] + redQ[1][r] + redQ[2][r] + redQ[3][r] +
                 redQ[4][r] + redQ[5][r] + redQ[6][r] + redQ[7][r]) * (1.0f / D);
    float rs = rsqrtf(var + 1e-5f);
#pragma unroll
    for (int nt = 0; nt < 2; ++nt) {
      int col = w * 32 + nt * 16 + c16;
      float o = (tv[nt][e] - mean[e]) * rs * g[col] + b[col];
      x[(size_t)row * D + col] = o;
      xb[(size_t)row * D + col] = f2bf(o);
    }
  }
}

// ---- pool phase 1: 64 blocks x 32 rows -> partial sum/max -----------------
__global__ __launch_bounds__(256) void k_pool1(const float* __restrict__ x,
                                               float* __restrict__ part) {
  int b = blockIdx.x, d = threadIdx.x;
  float sum = 0.f, mx = -INFINITY;
  for (int n = b * 32; n < b * 32 + 32; ++n) {
    float v = x[(size_t)n * D + d];
    sum += v;
    mx = fmaxf(mx, v);
  }
  part[(size_t)b * 2 * D + d] = sum;
  part[(size_t)b * 2 * D + D + d] = mx;
}

// ---- pool phase 2: reduce 64 partials + project ---------------------------
__global__ __launch_bounds__(256) void k_pool2(const float* __restrict__ part,
                                               const float* __restrict__ Wr,
                                               const float* __restrict__ br,
                                               float* __restrict__ out) {
  __shared__ float pooled[2 * D];
  int d = threadIdx.x;
  float sum = 0.f, mx = -INFINITY;
  for (int b = 0; b < 64; ++b) {
    sum += part[(size_t)b * 2 * D + d];
    mx = fmaxf(mx, part[(size_t)b * 2 * D + D + d]);
  }
  pooled[d] = sum * (1.0f / N);
  pooled[D + d] = mx;
  __syncthreads();
  float acc = br[d];
  for (int k2 = 0; k2 < 2 * D; ++k2) acc = fmaf(pooled[k2], Wr[(size_t)k2 * D + d], acc);
  out[d] = acc;
}

extern "C" void kernel_launch(void* const* d_in, const int* in_sizes, int n_in,
                              void* d_out, int out_size, void* d_ws, size_t ws_size,
                              hipStream_t stream) {
  const int* node_types = (const int*)d_in[0];
  const int* eidx = (const int*)d_in[1];
  const float* node_emb = (const float*)d_in[2];
  const float* Wq = (const float*)d_in[3];
  const float* Wk = (const float*)d_in[4];
  const float* Wv = (const float*)d_in[5];
  const float* Wo = (const float*)d_in[6];
  const float* bo = (const float*)d_in[7];
  const float* eb = (const float*)d_in[8];
  const float* W1 = (const float*)d_in[9];
  const float* b1 = (const float*)d_in[10];
  const float* W2 = (const float*)d_in[11];
  const float* b2 = (const float*)d_in[12];
  const float* g1 = (const float*)d_in[13];
  const float* be1 = (const float*)d_in[14];
  const float* g2 = (const float*)d_in[15];
  const float* be2 = (const float*)d_in[16];
  const float* Wr = (const float*)d_in[17];
  const float* br = (const float*)d_in[18];
  float* out = (float*)d_out;

  // workspace layout
  float* x = (float*)d_ws;                      // N*D fp32
  float* Opart = x + (size_t)N * D;             // JC*N*D fp32
  float* mpart = Opart + (size_t)JC * N * D;    // JC*N*H
  float* lpart = mpart + (size_t)JC * N * H;    // JC*N*H
  float* ppool = lpart + (size_t)JC * N * H;    // 64*2*D
  unsigned short* xb = (unsigned short*)(ppool + 64 * 2 * D);
  unsigned short* qb = xb + (size_t)N * D;
  unsigned short* kb = qb + (size_t)N * D;
  unsigned short* vtb = kb + (size_t)N * D;     // (D, N) head-major d
  unsigned short* wqkvb = vtb + (size_t)N * D;  // L x (768, 256)
  unsigned short* wob = wqkvb + (size_t)L * 768 * D;
  unsigned short* w1b = wob + (size_t)L * D * D;
  unsigned short* w2b = w1b + (size_t)L * DFF * D;
  unsigned char* e8 = (unsigned char*)(w2b + (size_t)L * D * DFF);  // N*N bytes

  k_e8<<<(N * N / 4) / 256, 256, 0, stream>>>(eidx, (unsigned int*)e8);

  dim3 tb(32, 8);
  k_wt4<<<dim3(D / 32, D / 32, L * 4), tb, 0, stream>>>(Wq, Wk, Wv, Wo, wqkvb, wob);
  k_wt<<<dim3(DFF / 32, D / 32, L), tb, 0, stream>>>(W1, (size_t)D * DFF, D, DFF, w1b, DFF * D);
  k_wt<<<dim3(D / 32, DFF / 32, L), tb, 0, stream>>>(W2, (size_t)DFF * D, DFF, D, w2b, D * DFF);

  k_embed<<<N, 256, 0, stream>>>(node_types, node_emb, x, xb);

  for (int l = 0; l < L; ++l) {
    k_mm_qkv<<<dim3(768 / 64, N / 64), 256, 0, stream>>>(
        xb, wqkvb + (size_t)l * 768 * D, qb, kb, vtb);

    k_attn<<<dim3(N / 16, JC), 512, 0, stream>>>(qb, kb, vtb, e8,
                                                 eb + (size_t)l * NEDGE * H,
                                                 Opart, mpart, lpart);

    k_wo<<<N / 16, 512, 0, stream>>>(Opart, mpart, lpart,
                                     wob + (size_t)l * D * D, bo + (size_t)l * D,
                                     g1 + (size_t)l * D, be1 + (size_t)l * D, x, xb);

    k_ffn<<<N / 16, 512, 0, stream>>>(xb, w1b + (size_t)l * DFF * D,
                                      w2b + (size_t)l * D * DFF,
                                      b1 + (size_t)l * DFF, b2 + (size_t)l * D,
                                      g2 + (size_t)l * D, be2 + (size_t)l * D, x, xb);
  }

  k_pool1<<<64, 256, 0, stream>>>(x, ppool);
  k_pool2<<<1, 256, 0, stream>>>(ppool, Wr, br, out);
}

// Round 7
// 494.188 us; speedup vs baseline: 1.0672x; 1.0012x over previous
//
#include <hip/hip_runtime.h>
#include <math.h>

#define N 2048
#define D 256
#define H 8
#define DK 32
#define L 4
#define DFF 1024
#define NEDGE 5
#define JC 4  // attention j-chunks (flash-decode split)

typedef short short8 __attribute__((ext_vector_type(8)));
typedef float floatx4 __attribute__((ext_vector_type(4)));

__device__ __forceinline__ unsigned short f2bf(float f) {
  unsigned int u = __float_as_uint(f);
  u += 0x7fffu + ((u >> 16) & 1u);
  return (unsigned short)(u >> 16);
}

__device__ __forceinline__ void async16(unsigned short* lds, const unsigned short* g) {
  __builtin_amdgcn_global_load_lds(
      (const __attribute__((address_space(1))) unsigned int*)g,
      (__attribute__((address_space(3))) unsigned int*)lds, 16, 0, 0);
}

// ---- eidx int32 -> uint8 --------------------------------------------------
__global__ __launch_bounds__(256) void k_e8(const int* __restrict__ e,
                                            unsigned int* __restrict__ e8) {
  int i = blockIdx.x * 256 + threadIdx.x;  // over N*N/4
  int4 v = ((const int4*)e)[i];
  e8[i] = (unsigned int)(v.x & 0xff) | ((unsigned int)(v.y & 0xff) << 8) |
          ((unsigned int)(v.z & 0xff) << 16) | ((unsigned int)(v.w & 0xff) << 24);
}

// ---- 4x D x D weight transpose+convert in one launch ----------------------
__global__ __launch_bounds__(256) void k_wt4(const float* __restrict__ Wq,
                                             const float* __restrict__ Wk,
                                             const float* __restrict__ Wv,
                                             const float* __restrict__ Wo,
                                             unsigned short* __restrict__ wqkvb,
                                             unsigned short* __restrict__ wob) {
  __shared__ float t[32][33];
  int z = blockIdx.z, l = z >> 2, which = z & 3;
  const float* s = (which == 0 ? Wq : which == 1 ? Wk : which == 2 ? Wv : Wo) + (size_t)l * D * D;
  unsigned short* d;
  int rowOff;
  if (which < 3) { d = wqkvb + (size_t)l * 768 * D; rowOff = which * 256; }
  else { d = wob + (size_t)l * D * D; rowOff = 0; }
  int n0 = blockIdx.x * 32, k0 = blockIdx.y * 32;
  int tx = threadIdx.x, ty = threadIdx.y;
#pragma unroll
  for (int i = 0; i < 32; i += 8) t[ty + i][tx] = s[(size_t)(k0 + ty + i) * D + n0 + tx];
  __syncthreads();
#pragma unroll
  for (int i = 0; i < 32; i += 8)
    d[(size_t)(rowOff + n0 + ty + i) * D + k0 + tx] = f2bf(t[tx][ty + i]);
}

// ---- generic weight transpose+convert: src fp32 (K_,N_) -> dst bf16 (N_,K_)
__global__ __launch_bounds__(256) void k_wt(const float* __restrict__ src, size_t srcL,
                                            int K_, int N_,
                                            unsigned short* __restrict__ dst, size_t dstL) {
  __shared__ float t[32][33];
  int l = blockIdx.z;
  const float* s = src + (size_t)l * srcL;
  unsigned short* d = dst + (size_t)l * dstL;
  int n0 = blockIdx.x * 32, k0 = blockIdx.y * 32;
  int tx = threadIdx.x, ty = threadIdx.y;
#pragma unroll
  for (int i = 0; i < 32; i += 8) t[ty + i][tx] = s[(size_t)(k0 + ty + i) * N_ + n0 + tx];
  __syncthreads();
#pragma unroll
  for (int i = 0; i < 32; i += 8)
    d[(size_t)(n0 + ty + i) * K_ + k0 + tx] = f2bf(t[tx][ty + i]);
}

// ---------------- embed ----------------------------------------------------
__global__ __launch_bounds__(256) void k_embed(const int* __restrict__ nt,
                                               const float* __restrict__ emb,
                                               float* __restrict__ x,
                                               unsigned short* __restrict__ xb) {
  int n = blockIdx.x, d = threadIdx.x;
  float v = emb[nt[n] * D + d];
  x[n * D + d] = v;
  xb[n * D + d] = f2bf(v);
}

// ---- fused QKV GEMM (2-panel BK=64): writes qb,kb (N,D) and vt (D,N) ------
__global__ __launch_bounds__(256) void k_mm_qkv(const unsigned short* __restrict__ A,
                                                const unsigned short* __restrict__ Bt,
                                                unsigned short* __restrict__ qb,
                                                unsigned short* __restrict__ kb,
                                                unsigned short* __restrict__ vtb) {
  const int K = D;
  __shared__ unsigned short As[2][64 * 32];
  __shared__ unsigned short Bs[2][64 * 32];
  int tid = threadIdx.x;
  int w = tid >> 6, lane = tid & 63, quad = lane >> 4, c16 = lane & 15;
  int bm = blockIdx.y * 64, bn = blockIdx.x * 64;
  int srow = w * 16 + (lane >> 2);
  int schk = (lane & 3) * 8;
  const unsigned short* gA = A + (size_t)(bm + srow) * K + schk;
  const unsigned short* gB = Bt + (size_t)(bn + srow) * K + schk;

  floatx4 acc[4] = {{0.f, 0.f, 0.f, 0.f}, {0.f, 0.f, 0.f, 0.f},
                    {0.f, 0.f, 0.f, 0.f}, {0.f, 0.f, 0.f, 0.f}};
  for (int k0 = 0; k0 < K; k0 += 64) {
#pragma unroll
    for (int p = 0; p < 2; ++p) {
      async16(&As[p][w * 512 + lane * 8], gA + k0 + p * 32);
      async16(&Bs[p][w * 512 + lane * 8], gB + k0 + p * 32);
    }
    __syncthreads();
#pragma unroll
    for (int p = 0; p < 2; ++p) {
      short8 a = *(const short8*)&As[p][(w * 16 + c16) * 32 + quad * 8];
#pragma unroll
      for (int nt = 0; nt < 4; ++nt) {
        short8 b = *(const short8*)&Bs[p][(nt * 16 + c16) * 32 + quad * 8];
        acc[nt] = __builtin_amdgcn_mfma_f32_16x16x32_bf16(a, b, acc[nt], 0, 0, 0);
      }
    }
    __syncthreads();
  }
#pragma unroll
  for (int nt = 0; nt < 4; ++nt) {
#pragma unroll
    for (int e = 0; e < 4; ++e) {
      int row = bm + w * 16 + quad * 4 + e;
      int col = bn + nt * 16 + c16;  // q:0-255, k:256-511, v:512-767
      unsigned short bv = f2bf(acc[nt][e]);
      if (col < 512) {
        unsigned short* dst = (col < 256) ? qb : kb;
        dst[(size_t)row * D + (col & 255)] = bv;
      } else {
        vtb[(size_t)(col - 512) * N + row] = bv;
      }
    }
  }
}

// ---- MFMA flash attention, j-split partials, hoisted loads ----------------
#define PB_STR 72
__global__ __launch_bounds__(512) void k_attn(const unsigned short* __restrict__ qb,
                                              const unsigned short* __restrict__ kb,
                                              const unsigned short* __restrict__ vt,
                                              const unsigned char* __restrict__ e8,
                                              const float* __restrict__ eb,
                                              float* __restrict__ Opart,
                                              float* __restrict__ mpart,
                                              float* __restrict__ lpart) {
  __shared__ unsigned short Pb[H][16 * PB_STR];
  __shared__ float ebh[H][NEDGE];
  const int tid = threadIdx.x;
  const int h = tid >> 6;
  const int lane = tid & 63;
  const int quad = lane >> 4;
  const int c16 = lane & 15;
  const int r0 = blockIdx.x * 16;
  const int jc = blockIdx.y;

  if (tid < NEDGE * H) ebh[tid % H][tid / H] = eb[tid];
  __syncthreads();

  short8 aq = *(const short8*)&qb[(size_t)(r0 + c16) * D + h * DK + quad * 8];

  float mrow[4] = {-INFINITY, -INFINITY, -INFINITY, -INFINITY};
  float lrow[4] = {0.f, 0.f, 0.f, 0.f};
  floatx4 O0 = {0.f, 0.f, 0.f, 0.f};
  floatx4 O1 = {0.f, 0.f, 0.f, 0.f};
  const float scale = 0.17677669529663688f;

  for (int j0 = jc * (N / JC); j0 < (jc + 1) * (N / JC); j0 += 64) {
    // ---- issue ALL global loads for this tile up front (overlap w/ MFMA) --
    short8 bk[4];
#pragma unroll
    for (int t = 0; t < 4; ++t)
      bk[t] = *(const short8*)&kb[(size_t)(j0 + t * 16 + c16) * D + h * DK + quad * 8];
    short8 pv00 = *(const short8*)&vt[(size_t)(h * DK + c16) * N + j0 + quad * 8];
    short8 pv01 = *(const short8*)&vt[(size_t)(h * DK + c16) * N + j0 + 32 + quad * 8];
    short8 pv10 = *(const short8*)&vt[(size_t)(h * DK + 16 + c16) * N + j0 + quad * 8];
    short8 pv11 = *(const short8*)&vt[(size_t)(h * DK + 16 + c16) * N + j0 + 32 + quad * 8];
    int ei[4][4];
#pragma unroll
    for (int t = 0; t < 4; ++t)
#pragma unroll
      for (int e = 0; e < 4; ++e)
        ei[t][e] = e8[(size_t)(r0 + quad * 4 + e) * N + j0 + t * 16 + c16];

    // ---- QK^T ----
    floatx4 Sc[4];
#pragma unroll
    for (int t = 0; t < 4; ++t) {
      floatx4 z = {0.f, 0.f, 0.f, 0.f};
      Sc[t] = __builtin_amdgcn_mfma_f32_16x16x32_bf16(aq, bk[t], z, 0, 0, 0);
    }
    float s[4][4];
#pragma unroll
    for (int t = 0; t < 4; ++t)
#pragma unroll
      for (int e = 0; e < 4; ++e)
        s[t][e] = Sc[t][e] * scale + ebh[h][ei[t][e]];

    // ---- online softmax ----
#pragma unroll
    for (int e = 0; e < 4; ++e) {
      float tm = fmaxf(fmaxf(s[0][e], s[1][e]), fmaxf(s[2][e], s[3][e]));
      tm = fmaxf(tm, __shfl_xor(tm, 1));
      tm = fmaxf(tm, __shfl_xor(tm, 2));
      tm = fmaxf(tm, __shfl_xor(tm, 4));
      tm = fmaxf(tm, __shfl_xor(tm, 8));
      float mn = fmaxf(mrow[e], tm);
      float alpha = __expf(mrow[e] - mn);
      mrow[e] = mn;
      float ps = 0.f;
#pragma unroll
      for (int t = 0; t < 4; ++t) {
        float p = __expf(s[t][e] - mn);
        s[t][e] = p;
        ps += p;
      }
      ps += __shfl_xor(ps, 1);
      ps += __shfl_xor(ps, 2);
      ps += __shfl_xor(ps, 4);
      ps += __shfl_xor(ps, 8);
      lrow[e] = lrow[e] * alpha + ps;
      O0[e] *= alpha;
      O1[e] *= alpha;
    }
    // ---- P (C-layout) -> wave-private LDS -> A-layout ----
#pragma unroll
    for (int t = 0; t < 4; ++t)
#pragma unroll
      for (int e = 0; e < 4; ++e)
        Pb[h][(quad * 4 + e) * PB_STR + t * 16 + c16] = f2bf(s[t][e]);
    asm volatile("" ::: "memory");
    short8 ap0 = *(const short8*)&Pb[h][c16 * PB_STR + quad * 8];
    short8 ap1 = *(const short8*)&Pb[h][c16 * PB_STR + 32 + quad * 8];
    O0 = __builtin_amdgcn_mfma_f32_16x16x32_bf16(ap0, pv00, O0, 0, 0, 0);
    O0 = __builtin_amdgcn_mfma_f32_16x16x32_bf16(ap1, pv01, O0, 0, 0, 0);
    O1 = __builtin_amdgcn_mfma_f32_16x16x32_bf16(ap0, pv10, O1, 0, 0, 0);
    O1 = __builtin_amdgcn_mfma_f32_16x16x32_bf16(ap1, pv11, O1, 0, 0, 0);
    asm volatile("" ::: "memory");
  }

#pragma unroll
  for (int e = 0; e < 4; ++e) {
    int row = r0 + quad * 4 + e;
    size_t ob = ((size_t)jc * N + row) * D + h * DK;
    Opart[ob + c16] = O0[e];
    Opart[ob + 16 + c16] = O1[e];
    if (c16 == 0) {
      mpart[((size_t)jc * N + row) * H + h] = mrow[e];
      lpart[((size_t)jc * N + row) * H + h] = lrow[e];
    }
  }
}

// ---- fused: combine partials -> Wo GEMM -> bias+residual+LN1 --------------
// grid N/8 = 256 blocks, 512 threads (8 waves), 8 rows/block.
// MFMA A-frag duplicates the 8 rows into both 16-row halves; writes quad<2.
#define AO_STR 272
__global__ __launch_bounds__(512) void k_wo(const float* __restrict__ Opart,
                                            const float* __restrict__ mpart,
                                            const float* __restrict__ lpart,
                                            const unsigned short* __restrict__ wob,
                                            const float* __restrict__ bias,
                                            const float* __restrict__ g,
                                            const float* __restrict__ b,
                                            float* __restrict__ x,
                                            unsigned short* __restrict__ xb) {
  __shared__ unsigned short ao_s[8 * AO_STR];
  __shared__ float redS[8][16];
  __shared__ float redQ[8][16];
  const int tid = threadIdx.x;
  const int w = tid >> 6, lane = tid & 63, quad = lane >> 4, c16 = lane & 15;
  const int r0 = blockIdx.x * 8;

  // ---- combine: 8 rows x 256 cols; thread: 4 cols of one row ----
  {
    int trow = tid >> 6;           // 0..7
    int tcol = (tid & 63) * 4;     // 0..252
    int hh = tcol >> 5;
    int row = r0 + trow;
    float m[JC], mstar = -INFINITY;
#pragma unroll
    for (int c = 0; c < JC; ++c) {
      m[c] = mpart[((size_t)c * N + row) * H + hh];
      mstar = fmaxf(mstar, m[c]);
    }
    float lstar = 0.f;
    float o[4] = {};
#pragma unroll
    for (int c = 0; c < JC; ++c) {
      float wgt = __expf(m[c] - mstar);
      lstar += wgt * lpart[((size_t)c * N + row) * H + hh];
      float4 v0 = *(const float4*)(Opart + ((size_t)c * N + row) * D + tcol);
      o[0] += wgt * v0.x; o[1] += wgt * v0.y; o[2] += wgt * v0.z; o[3] += wgt * v0.w;
    }
    float inv = 1.0f / lstar;
#pragma unroll
    for (int j = 0; j < 4; ++j) ao_s[trow * AO_STR + tcol + j] = f2bf(o[j] * inv);
  }
  __syncthreads();

  // ---- Wo GEMM: wave w cols [w*32, +32), K=256, B direct from global ----
  floatx4 acc[2] = {{0.f, 0.f, 0.f, 0.f}, {0.f, 0.f, 0.f, 0.f}};
#pragma unroll
  for (int kc = 0; kc < 8; ++kc) {
    short8 a = *(const short8*)&ao_s[(c16 & 7) * AO_STR + kc * 32 + quad * 8];
#pragma unroll
    for (int nt = 0; nt < 2; ++nt) {
      int col = w * 32 + nt * 16 + c16;
      short8 bf = *(const short8*)&wob[(size_t)col * D + kc * 32 + quad * 8];
      acc[nt] = __builtin_amdgcn_mfma_f32_16x16x32_bf16(a, bf, acc[nt], 0, 0, 0);
    }
  }

  // ---- epilogue: bias + residual + LN (rows duplicated; write quad<2) ----
  float tv[2][4];
  float ps[4];
#pragma unroll
  for (int e = 0; e < 4; ++e) {
    int row = r0 + ((quad * 4 + e) & 7);
    float s = 0.f;
#pragma unroll
    for (int nt = 0; nt < 2; ++nt) {
      int col = w * 32 + nt * 16 + c16;
      float v = acc[nt][e] + bias[col] + x[(size_t)row * D + col];
      tv[nt][e] = v;
      s += v;
    }
    s += __shfl_xor(s, 1); s += __shfl_xor(s, 2);
    s += __shfl_xor(s, 4); s += __shfl_xor(s, 8);
    ps[e] = s;
  }
  if (c16 == 0) {
#pragma unroll
    for (int e = 0; e < 4; ++e) redS[w][quad * 4 + e] = ps[e];
  }
  __syncthreads();
  float mean[4];
#pragma unroll
  for (int e = 0; e < 4; ++e) {
    int r = quad * 4 + e;
    mean[e] = (redS[0][r] + redS[1][r] + redS[2][r] + redS[3][r] +
               redS[4][r] + redS[5][r] + redS[6][r] + redS[7][r]) * (1.0f / D);
    float q = 0.f;
#pragma unroll
    for (int nt = 0; nt < 2; ++nt) {
      float c_ = tv[nt][e] - mean[e];
      q += c_ * c_;
    }
    q += __shfl_xor(q, 1); q += __shfl_xor(q, 2);
    q += __shfl_xor(q, 4); q += __shfl_xor(q, 8);
    ps[e] = q;
  }
  if (c16 == 0) {
#pragma unroll
    for (int e = 0; e < 4; ++e) redQ[w][quad * 4 + e] = ps[e];
  }
  __syncthreads();
#pragma unroll
  for (int e = 0; e < 4; ++e) {
    int r = quad * 4 + e;
    int row = r0 + (r & 7);
    float var = (redQ[0][r] + redQ[1][r] + redQ[2][r] + redQ[3][r] +
                 redQ[4][r] + redQ[5][r] + redQ[6][r] + redQ[7][r]) * (1.0f / D);
    float rs = rsqrtf(var + 1e-5f);
    if (quad < 2) {
#pragma unroll
      for (int nt = 0; nt < 2; ++nt) {
        int col = w * 32 + nt * 16 + c16;
        float o = (tv[nt][e] - mean[e]) * rs * g[col] + b[col];
        x[(size_t)row * D + col] = o;
        xb[(size_t)row * D + col] = f2bf(o);
      }
    }
  }
}

// ---- fused FFN: GEMM1+bias+GELU -> LDS -> GEMM2+bias+residual+LN2 ---------
// grid N/8 = 256 blocks, 512 threads (8 waves), 8 rows/block.
#define HS_STR 1040
__global__ __launch_bounds__(512) void k_ffn(const unsigned short* __restrict__ xbin,
                                             const unsigned short* __restrict__ w1b,
                                             const unsigned short* __restrict__ w2b,
                                             const float* __restrict__ b1,
                                             const float* __restrict__ b2,
                                             const float* __restrict__ g,
                                             const float* __restrict__ b,
                                             float* __restrict__ x,
                                             unsigned short* __restrict__ xb) {
  __shared__ unsigned short hs[8 * HS_STR];
  __shared__ float redS[8][16];
  __shared__ float redQ[8][16];
  const int tid = threadIdx.x;
  const int w = tid >> 6, lane = tid & 63, quad = lane >> 4, c16 = lane & 15;
  const int r0 = blockIdx.x * 8;

  // ---- phase 1: FFN1, 8 rows x 128 cols per wave ----
  floatx4 acc1[8];
#pragma unroll
  for (int nt = 0; nt < 8; ++nt) acc1[nt] = (floatx4){0.f, 0.f, 0.f, 0.f};
#pragma unroll
  for (int kc = 0; kc < 8; ++kc) {
    short8 a = *(const short8*)&xbin[(size_t)(r0 + (c16 & 7)) * D + kc * 32 + quad * 8];
#pragma unroll
    for (int nt = 0; nt < 8; ++nt) {
      int col = w * 128 + nt * 16 + c16;
      short8 bf = *(const short8*)&w1b[(size_t)col * D + kc * 32 + quad * 8];
      acc1[nt] = __builtin_amdgcn_mfma_f32_16x16x32_bf16(a, bf, acc1[nt], 0, 0, 0);
    }
  }
  if (quad < 2) {
#pragma unroll
    for (int nt = 0; nt < 8; ++nt) {
#pragma unroll
      for (int e = 0; e < 4; ++e) {
        int col = w * 128 + nt * 16 + c16;
        float v = acc1[nt][e] + b1[col];
        v = 0.5f * v * (1.0f + erff(v * 0.70710678118654752f));
        hs[(quad * 4 + e) * HS_STR + col] = f2bf(v);
      }
    }
  }
  __syncthreads();

  // ---- phase 2: FFN2, 8 rows x 32 cols per wave, K=1024 ----
  floatx4 acc2[2] = {{0.f, 0.f, 0.f, 0.f}, {0.f, 0.f, 0.f, 0.f}};
#pragma unroll 8
  for (int kc = 0; kc < 32; ++kc) {
    short8 a = *(const short8*)&hs[(c16 & 7) * HS_STR + kc * 32 + quad * 8];
#pragma unroll
    for (int nt = 0; nt < 2; ++nt) {
      int col = w * 32 + nt * 16 + c16;
      short8 bf = *(const short8*)&w2b[(size_t)col * DFF + kc * 32 + quad * 8];
      acc2[nt] = __builtin_amdgcn_mfma_f32_16x16x32_bf16(a, bf, acc2[nt], 0, 0, 0);
    }
  }

  // ---- epilogue: bias + residual + LN2 ----
  float tv[2][4];
  float ps[4];
#pragma unroll
  for (int e = 0; e < 4; ++e) {
    int row = r0 + ((quad * 4 + e) & 7);
    float s = 0.f;
#pragma unroll
    for (int nt = 0; nt < 2; ++nt) {
      int col = w * 32 + nt * 16 + c16;
      float v = acc2[nt][e] + b2[col] + x[(size_t)row * D + col];
      tv[nt][e] = v;
      s += v;
    }
    s += __shfl_xor(s, 1); s += __shfl_xor(s, 2);
    s += __shfl_xor(s, 4); s += __shfl_xor(s, 8);
    ps[e] = s;
  }
  if (c16 == 0) {
#pragma unroll
    for (int e = 0; e < 4; ++e) redS[w][quad * 4 + e] = ps[e];
  }
  __syncthreads();
  float mean[4];
#pragma unroll
  for (int e = 0; e < 4; ++e) {
    int r = quad * 4 + e;
    mean[e] = (redS[0][r] + redS[1][r] + redS[2][r] + redS[3][r] +
               redS[4][r] + redS[5][r] + redS[6][r] + redS[7][r]) * (1.0f / D);
    float q = 0.f;
#pragma unroll
    for (int nt = 0; nt < 2; ++nt) {
      float c_ = tv[nt][e] - mean[e];
      q += c_ * c_;
    }
    q += __shfl_xor(q, 1); q += __shfl_xor(q, 2);
    q += __shfl_xor(q, 4); q += __shfl_xor(q, 8);
    ps[e] = q;
  }
  if (c16 == 0) {
#pragma unroll
    for (int e = 0; e < 4; ++e) redQ[w][quad * 4 + e] = ps[e];
  }
  __syncthreads();
#pragma unroll
  for (int e = 0; e < 4; ++e) {
    int r = quad * 4 + e;
    int row = r0 + (r & 7);
    float var = (redQ[0][r] + redQ[1][r] + redQ[2][r] + redQ[3][r] +
                 redQ[4][r] + redQ[5][r] + redQ[6][r] + redQ[7][r]) * (1.0f / D);
    float rs = rsqrtf(var + 1e-5f);
    if (quad < 2) {
#pragma unroll
      for (int nt = 0; nt < 2; ++nt) {
        int col = w * 32 + nt * 16 + c16;
        float o = (tv[nt][e] - mean[e]) * rs * g[col] + b[col];
        x[(size_t)row * D + col] = o;
        xb[(size_t)row * D + col] = f2bf(o);
      }
    }
  }
}

// ---- pool phase 1: 64 blocks x 32 rows -> partial sum/max -----------------
__global__ __launch_bounds__(256) void k_pool1(const float* __restrict__ x,
                                               float* __restrict__ part) {
  int b = blockIdx.x, d = threadIdx.x;
  float sum = 0.f, mx = -INFINITY;
  for (int n = b * 32; n < b * 32 + 32; ++n) {
    float v = x[(size_t)n * D + d];
    sum += v;
    mx = fmaxf(mx, v);
  }
  part[(size_t)b * 2 * D + d] = sum;
  part[(size_t)b * 2 * D + D + d] = mx;
}

// ---- pool phase 2: reduce 64 partials + project ---------------------------
__global__ __launch_bounds__(256) void k_pool2(const float* __restrict__ part,
                                               const float* __restrict__ Wr,
                                               const float* __restrict__ br,
                                               float* __restrict__ out) {
  __shared__ float pooled[2 * D];
  int d = threadIdx.x;
  float sum = 0.f, mx = -INFINITY;
  for (int b = 0; b < 64; ++b) {
    sum += part[(size_t)b * 2 * D + d];
    mx = fmaxf(mx, part[(size_t)b * 2 * D + D + d]);
  }
  pooled[d] = sum * (1.0f / N);
  pooled[D + d] = mx;
  __syncthreads();
  float acc = br[d];
  for (int k2 = 0; k2 < 2 * D; ++k2) acc = fmaf(pooled[k2], Wr[(size_t)k2 * D + d], acc);
  out[d] = acc;
}

extern "C" void kernel_launch(void* const* d_in, const int* in_sizes, int n_in,
                              void* d_out, int out_size, void* d_ws, size_t ws_size,
                              hipStream_t stream) {
  const int* node_types = (const int*)d_in[0];
  const int* eidx = (const int*)d_in[1];
  const float* node_emb = (const float*)d_in[2];
  const float* Wq = (const float*)d_in[3];
  const float* Wk = (const float*)d_in[4];
  const float* Wv = (const float*)d_in[5];
  const float* Wo = (const float*)d_in[6];
  const float* bo = (const float*)d_in[7];
  const float* eb = (const float*)d_in[8];
  const float* W1 = (const float*)d_in[9];
  const float* b1 = (const float*)d_in[10];
  const float* W2 = (const float*)d_in[11];
  const float* b2 = (const float*)d_in[12];
  const float* g1 = (const float*)d_in[13];
  const float* be1 = (const float*)d_in[14];
  const float* g2 = (const float*)d_in[15];
  const float* be2 = (const float*)d_in[16];
  const float* Wr = (const float*)d_in[17];
  const float* br = (const float*)d_in[18];
  float* out = (float*)d_out;

  // workspace layout
  float* x = (float*)d_ws;                      // N*D fp32
  float* Opart = x + (size_t)N * D;             // JC*N*D fp32
  float* mpart = Opart + (size_t)JC * N * D;    // JC*N*H
  float* lpart = mpart + (size_t)JC * N * H;    // JC*N*H
  float* ppool = lpart + (size_t)JC * N * H;    // 64*2*D
  unsigned short* xb = (unsigned short*)(ppool + 64 * 2 * D);
  unsigned short* qb = xb + (size_t)N * D;
  unsigned short* kb = qb + (size_t)N * D;
  unsigned short* vtb = kb + (size_t)N * D;     // (D, N) head-major d
  unsigned short* wqkvb = vtb + (size_t)N * D;  // L x (768, 256)
  unsigned short* wob = wqkvb + (size_t)L * 768 * D;
  unsigned short* w1b = wob + (size_t)L * D * D;
  unsigned short* w2b = w1b + (size_t)L * DFF * D;
  unsigned char* e8 = (unsigned char*)(w2b + (size_t)L * D * DFF);  // N*N bytes

  k_e8<<<(N * N / 4) / 256, 256, 0, stream>>>(eidx, (unsigned int*)e8);

  dim3 tb(32, 8);
  k_wt4<<<dim3(D / 32, D / 32, L * 4), tb, 0, stream>>>(Wq, Wk, Wv, Wo, wqkvb, wob);
  k_wt<<<dim3(DFF / 32, D / 32, L), tb, 0, stream>>>(W1, (size_t)D * DFF, D, DFF, w1b, DFF * D);
  k_wt<<<dim3(D / 32, DFF / 32, L), tb, 0, stream>>>(W2, (size_t)DFF * D, DFF, D, w2b, D * DFF);

  k_embed<<<N, 256, 0, stream>>>(node_types, node_emb, x, xb);

  for (int l = 0; l < L; ++l) {
    k_mm_qkv<<<dim3(768 / 64, N / 64), 256, 0, stream>>>(
        xb, wqkvb + (size_t)l * 768 * D, qb, kb, vtb);

    k_attn<<<dim3(N / 16, JC), 512, 0, stream>>>(qb, kb, vtb, e8,
                                                 eb + (size_t)l * NEDGE * H,
                                                 Opart, mpart, lpart);

    k_wo<<<N / 8, 512, 0, stream>>>(Opart, mpart, lpart,
                                    wob + (size_t)l * D * D, bo + (size_t)l * D,
                                    g1 + (size_t)l * D, be1 + (size_t)l * D, x, xb);

    k_ffn<<<N / 8, 512, 0, stream>>>(xb, w1b + (size_t)l * DFF * D,
                                     w2b + (size_t)l * D * DFF,
                                     b1 + (size_t)l * DFF, b2 + (size_t)l * D,
                                     g2 + (size_t)l * D, be2 + (size_t)l * D, x, xb);
  }

  k_pool1<<<64, 256, 0, stream>>>(x, ppool);
  k_pool2<<<1, 256, 0, stream>>>(ppool, Wr, br, out);
}